// Round 15
// baseline (333.807 us; speedup 1.0000x reference)
//
#include <hip/hip_runtime.h>
#include <hip/hip_bf16.h>
#include <stdint.h>

// Problem constants (from reference)
#define NN 50000
#define EE 800000
#define FF 128
#define HH 3
#define CC 64
#define GG 16
#define NCLS 10
#define HC (HH*CC)   // 192

#define LOG2E 1.4426950408889634f

typedef uint16_t u16;
typedef __attribute__((ext_vector_type(8))) short short8;
typedef __attribute__((ext_vector_type(4))) float f32x4;
typedef __attribute__((ext_vector_type(2))) _Float16 f16x2;

// ---------------------------------------------------------------------------
// bf16 RNE + fp16 bit helpers
// ---------------------------------------------------------------------------
__device__ __forceinline__ u16 bf16_rne(float x) {
    uint32_t u = __float_as_uint(x);
    u += 0x7fffu + ((u >> 16) & 1u);
    return (u16)(u >> 16);
}
__device__ __forceinline__ u16 f16_bits(float x) {
    _Float16 h = (_Float16)x;
    return __builtin_bit_cast(unsigned short, h);
}

// ---------------------------------------------------------------------------
// 16-lane (quarter-wave) sum via DPP row-scan + lane15 broadcast.
// ---------------------------------------------------------------------------
__device__ __forceinline__ float qsum16(float x) {
    #define DPP_ADD(ctrl) \
        x += __int_as_float(__builtin_amdgcn_update_dpp(0, __float_as_int(x), ctrl, 0xf, 0xf, true))
    DPP_ADD(0x111);  // row_shr:1
    DPP_ADD(0x112);  // row_shr:2
    DPP_ADD(0x114);  // row_shr:4
    DPP_ADD(0x118);  // row_shr:8
    #undef DPP_ADD
    return __int_as_float(__builtin_amdgcn_ds_swizzle(__float_as_int(x), 0x1F0));
}

// ---------------------------------------------------------------------------
// CSR build (WITH explicit self-loops)
// ---------------------------------------------------------------------------
__global__ void count_deg(const int* __restrict__ dst, int* __restrict__ deg, int E) {
    int i = blockIdx.x * blockDim.x + threadIdx.x;
    if (i < E) atomicAdd(&deg[dst[i]], 1);
}

__global__ __launch_bounds__(256) void scan_local(const int* __restrict__ deg,
                                                  int* __restrict__ rowp1,
                                                  int* __restrict__ partials, int n) {
    __shared__ int sums[256];
    int base = blockIdx.x * 2048 + threadIdx.x * 8;
    int v[8]; int run = 0;
    #pragma unroll
    for (int i = 0; i < 8; ++i) {
        int x = (base + i < n) ? deg[base + i] + 1 : 0;   // +1: self-loop slot
        run += x; v[i] = run;
    }
    sums[threadIdx.x] = run;
    __syncthreads();
    for (int off = 1; off < 256; off <<= 1) {
        int t = (threadIdx.x >= off) ? sums[threadIdx.x - off] : 0;
        __syncthreads();
        sums[threadIdx.x] += t;
        __syncthreads();
    }
    int prefix = (threadIdx.x > 0) ? sums[threadIdx.x - 1] : 0;
    #pragma unroll
    for (int i = 0; i < 8; ++i)
        if (base + i < n) rowp1[base + i] = v[i] + prefix;
    if (threadIdx.x == 255) partials[blockIdx.x] = sums[255];
}

// Fused: partials exclusive-prefix, rowp finalize, cursor init, self-loop write.
__global__ __launch_bounds__(256) void scan_finish(
    int* __restrict__ rowp, int* __restrict__ cursor, const int* __restrict__ partials,
    int* __restrict__ colv, int n, int nchunks) {
    __shared__ int pre[32];
    int t = threadIdx.x;
    if (t < 32) {
        int s = 0;
        for (int b = 0; b < nchunks && b < t; ++b) s += partials[b];
        pre[t] = s;
    }
    __syncthreads();
    int i = blockIdx.x * blockDim.x + t;
    if (i == 0) { rowp[0] = 0; cursor[0] = 0; }
    if (i < n) {
        int v = rowp[1 + i] + pre[i >> 11];
        rowp[1 + i] = v;
        colv[v - 1] = i;                 // self-loop in last slot of row i
        if (i < n - 1) cursor[i + 1] = v;
    }
}

__global__ void fill_csr(const int* __restrict__ src, const int* __restrict__ dst,
                         int* __restrict__ cursor, int* __restrict__ colv, int E) {
    int i = blockIdx.x * blockDim.x + threadIdx.x;
    if (i < E) {
        int pos = atomicAdd(&cursor[dst[i]], 1);
        colv[pos] = src[i];
    }
}

// ---------------------------------------------------------------------------
// Prep weights: [K][192] fp32 -> FRAG-MAJOR bf16 (MFMA B operand).
// Also zeroes the pool/cnt accumulators.
// ---------------------------------------------------------------------------
__global__ void prep_all(const float* __restrict__ Wl1, const float* __restrict__ Wr1,
                         const float* __restrict__ Wl2, const float* __restrict__ Wr2,
                         u16* l1, u16* r1, u16* l2, u16* r2,
                         float* __restrict__ pool) {
    int idx = blockIdx.x * blockDim.x + threadIdx.x;
    if (idx < GG * (CC + 1)) pool[idx] = 0.f;
    const int S1 = FF * HC, S2 = HC * HC;
    const float* B; u16* H; int K, f;
    if (idx < S1)                { B = Wl1; H = l1; K = FF; f = idx; }
    else if (idx < 2*S1)         { B = Wr1; H = r1; K = FF; f = idx - S1; }
    else if (idx < 2*S1 + S2)    { B = Wl2; H = l2; K = HC; f = idx - 2*S1; }
    else if (idx < 2*S1 + 2*S2)  { B = Wr2; H = r2; K = HC; f = idx - 2*S1 - S2; }
    else return;
    const int KB = K / 32;
    int j    = f & 7;
    int lane = (f >> 3) & 63;
    int rest = f >> 9;
    int kb    = rest % KB;
    int ntile = rest / KB;
    int n = ntile * 16 + (lane & 15);
    int k = kb * 32 + (lane >> 4) * 8 + j;
    H[f] = bf16_rne(B[k * HC + n]);
}

// ---------------------------------------------------------------------------
// Pure-bf16 MFMA dual GEMM: C1 = A@B1, C2 = A@B2, both emitted as packed FP16
// gather layout [node][16 lane-groups][3 head][4 chan] (384B/row):
//   u16 index of (chan c, head h) = (c>>2)*12 + h*4 + (c&3)
// 32-row M-tiles; A frags direct from global; CVTIN: fp32 A -> bf16 in-reg.
// LDS only for epilogue repack -> coalesced dwordx4 stores.
// ---------------------------------------------------------------------------
template<int K, bool CVTIN>
__global__ __launch_bounds__(256) void mfma_gemm(
    const float* __restrict__ Af, const u16* __restrict__ Ab,
    const u16* __restrict__ B1, const u16* __restrict__ B2,
    u16* __restrict__ C1p, u16* __restrict__ C2p, int M)
{
    constexpr int KB = K / 32;
    __shared__ __align__(16) u16 smem[32 * 256];

    const int tid  = threadIdx.x;
    const int w    = tid >> 6;
    const int lane = tid & 63;
    const int m0   = blockIdx.x * 32;
    const int frow = lane & 15;
    const int fkc  = lane >> 4;

    f32x4 acc[2][3][2];
    #pragma unroll
    for (int mt = 0; mt < 2; ++mt)
        #pragma unroll
        for (int nt = 0; nt < 3; ++nt)
            #pragma unroll
            for (int rt = 0; rt < 2; ++rt)
                acc[mt][nt][rt] = (f32x4){0.f, 0.f, 0.f, 0.f};

    int arow[2];
    arow[0] = min(m0 + frow, M - 1);
    arow[1] = min(m0 + 16 + frow, M - 1);

    const u16* bb[2][3];
    #pragma unroll
    for (int mt = 0; mt < 2; ++mt)
        #pragma unroll
        for (int nt = 0; nt < 3; ++nt)
            bb[mt][nt] = (mt ? B2 : B1) + ((size_t)(w * 3 + nt) * KB * 64 + lane) * 8;

    #pragma unroll
    for (int kb = 0; kb < KB; ++kb) {
        short8 af[2];
        #pragma unroll
        for (int rt = 0; rt < 2; ++rt) {
            if constexpr (CVTIN) {
                const float* ap = Af + (size_t)arow[rt] * K + kb * 32 + fkc * 8;
                float4 a0 = *(const float4*)ap;
                float4 a1 = *(const float4*)(ap + 4);
                af[rt] = (short8){(short)bf16_rne(a0.x), (short)bf16_rne(a0.y),
                                  (short)bf16_rne(a0.z), (short)bf16_rne(a0.w),
                                  (short)bf16_rne(a1.x), (short)bf16_rne(a1.y),
                                  (short)bf16_rne(a1.z), (short)bf16_rne(a1.w)};
            } else {
                af[rt] = *(const short8*)(Ab + (size_t)arow[rt] * K + kb * 32 + fkc * 8);
            }
        }
        #pragma unroll
        for (int mt = 0; mt < 2; ++mt)
            #pragma unroll
            for (int nt = 0; nt < 3; ++nt) {
                short8 b = *(const short8*)(bb[mt][nt] + kb * 512);
                #pragma unroll
                for (int rt = 0; rt < 2; ++rt)
                    acc[mt][nt][rt] = __builtin_amdgcn_mfma_f32_16x16x32_bf16(af[rt], b, acc[mt][nt][rt], 0, 0, 0);
            }
    }

    // ---- epilogue: repack through LDS (padded 256-u16 rows), coalesced stores
    const int q4 = (lane >> 4) * 4;
    #pragma unroll
    for (int mt = 0; mt < 2; ++mt) {
        __syncthreads();
        #pragma unroll
        for (int nt = 0; nt < 3; ++nt) {
            int col = w * 48 + nt * 16 + frow;   // 0..191
            int c = col & 63, h = col >> 6;
            int u = (c >> 2) * 12 + h * 4 + (c & 3);   // fp16 pair-packed layout
            int chunk = u >> 3, within = u & 7;
            #pragma unroll
            for (int rt = 0; rt < 2; ++rt)
                #pragma unroll
                for (int r = 0; r < 4; ++r) {
                    int lrow = rt * 16 + q4 + r;
                    smem[lrow * 256 + ((chunk ^ (lrow & 7)) << 3) + within] =
                        f16_bits(acc[mt][nt][rt][r]);
                }
        }
        __syncthreads();
        u16* C = mt ? C2p : C1p;
        #pragma unroll
        for (int i = 0; i < 3; ++i) {
            int idx  = tid + 256 * i;       // 16B chunk id, 0..767
            int lrow = idx / 24;
            int coff = idx % 24;
            if (m0 + lrow < M)
                *(uint4*)(C + (size_t)(m0 + lrow) * HC + coff * 8) =
                    *(const uint4*)&smem[lrow * 256 + ((coff ^ (lrow & 7)) << 3)];
        }
    }
}

// ---------------------------------------------------------------------------
// GATv2 aggregation: PERSISTENT waves — each wave processes ~n/8192 nodes,
// grid-strided (evens out degree variance; att pack hoisted out of the node
// loop). Per node: FOUR edges per wave (one per 16-lane quarter), 4 channels
// per lane, 24B fp16 gather ([head][4chan] per lane). Packed-f16 add/leaky +
// v_dot2_f32_f16 dot; f32 p*v accumulation (r12 form — best measured).
// Self-loops are IN the CSR. DPP row-scan reduce; no-max softmax (exp2).
// ---------------------------------------------------------------------------
template<bool MASK>
__device__ __forceinline__ void gat_quad(
    int i0, int q, int l, int beg, int cnt, int cm1,
    const int* __restrict__ colv, const u16* __restrict__ xlp,
    const f16x2 attv[3][2], const f16x2 xrv[3][2],
    float s[3], float acc[3][4])
{
    int idx = i0 + q;
    int iq  = MASK ? min(idx, cm1) : idx;
    int src = colv[beg + iq];
    const u16* p = xlp + (size_t)src * HC + l * 12;
    uint4 q0 = *(const uint4*)p;
    uint2 q1 = *(const uint2*)(p + 8);
    f16x2 vp[3][2];
    vp[0][0] = __builtin_bit_cast(f16x2, q0.x);
    vp[0][1] = __builtin_bit_cast(f16x2, q0.y);
    vp[1][0] = __builtin_bit_cast(f16x2, q0.z);
    vp[1][1] = __builtin_bit_cast(f16x2, q0.w);
    vp[2][0] = __builtin_bit_cast(f16x2, q1.x);
    vp[2][1] = __builtin_bit_cast(f16x2, q1.y);
    const f16x2 k02 = {(_Float16)0.2f, (_Float16)0.2f};
    #pragma unroll
    for (int r = 0; r < 3; ++r) {
        f16x2 t0 = vp[r][0] + xrv[r][0];
        f16x2 t1 = vp[r][1] + xrv[r][1];
        t0 = __builtin_elementwise_max(t0, t0 * k02);
        t1 = __builtin_elementwise_max(t1, t1 * k02);
        float d = __builtin_amdgcn_fdot2(t0, attv[r][0], 0.f, false);
        d = __builtin_amdgcn_fdot2(t1, attv[r][1], d, false);
        d = qsum16(d);
        float pe = __builtin_amdgcn_exp2f(d);
        if (MASK) pe = (idx < cnt) ? pe : 0.f;
        s[r] += pe;
        acc[r][0] = fmaf(pe, (float)vp[r][0][0], acc[r][0]);
        acc[r][1] = fmaf(pe, (float)vp[r][0][1], acc[r][1]);
        acc[r][2] = fmaf(pe, (float)vp[r][1][0], acc[r][2]);
        acc[r][3] = fmaf(pe, (float)vp[r][1][1], acc[r][3]);
    }
}

#define GAT_BLOCKS 2048
template<int CONCAT>
__global__ __launch_bounds__(256) void gat_agg(
    const u16* __restrict__ xlp, const u16* __restrict__ xrp,
    const int* __restrict__ rowp, const int* __restrict__ colv,
    const float* __restrict__ att, const float* __restrict__ bias,
    float* __restrict__ out, u16* __restrict__ oh1, int n)
{
    const int wave = threadIdx.x >> 6;
    const int lane = threadIdx.x & 63;
    const int wid  = blockIdx.x * 4 + wave;
    const int wtot = GAT_BLOCKS * 4;
    const int q = lane >> 4;   // quarter = edge slot
    const int l = lane & 15;   // channel group (channels 4l..4l+3)

    // node-invariant: att pack (hoisted out of node loop)
    f16x2 attv[3][2];
    #pragma unroll
    for (int r = 0; r < 3; ++r) {
        float4 a4 = *(const float4*)(att + r * 64 + 4 * l);
        attv[r][0] = (f16x2){(_Float16)(a4.x * LOG2E), (_Float16)(a4.y * LOG2E)};
        attv[r][1] = (f16x2){(_Float16)(a4.z * LOG2E), (_Float16)(a4.w * LOG2E)};
    }

    for (int node0 = wid; node0 < n; node0 += wtot) {
        const int node = __builtin_amdgcn_readfirstlane(node0);

        f16x2 xrv[3][2];
        {
            const u16* p = xrp + (size_t)node * HC + l * 12;
            uint4 x0 = *(const uint4*)p;
            uint2 x1 = *(const uint2*)(p + 8);
            xrv[0][0] = __builtin_bit_cast(f16x2, x0.x);
            xrv[0][1] = __builtin_bit_cast(f16x2, x0.y);
            xrv[1][0] = __builtin_bit_cast(f16x2, x0.z);
            xrv[1][1] = __builtin_bit_cast(f16x2, x0.w);
            xrv[2][0] = __builtin_bit_cast(f16x2, x1.x);
            xrv[2][1] = __builtin_bit_cast(f16x2, x1.y);
        }

        float s[3] = {0.f, 0.f, 0.f};
        float acc[3][4] = {{0.f}};

        const int beg = rowp[node];
        const int cnt = rowp[node + 1] - beg;   // includes self-loop
        const int cm1 = cnt - 1;

        int i0 = 0;
        const int nfull = cnt & ~3;
        #pragma unroll 2
        for (; i0 < nfull; i0 += 4)
            gat_quad<false>(i0, q, l, beg, cnt, cm1, colv, xlp, attv, xrv, s, acc);
        if (i0 < cnt)
            gat_quad<true>(i0, q, l, beg, cnt, cm1, colv, xlp, attv, xrv, s, acc);

        // combine quarters (xor16) and halves (xor32)
        #pragma unroll
        for (int r = 0; r < 3; ++r) {
            s[r] += __shfl_xor(s[r], 16, 64);
            s[r] += __shfl_xor(s[r], 32, 64);
            #pragma unroll
            for (int j = 0; j < 4; ++j) {
                acc[r][j] += __shfl_xor(acc[r][j], 16, 64);
                acc[r][j] += __shfl_xor(acc[r][j], 32, 64);
            }
        }

        if (CONCAT) {
            if (lane < 48) {
                int r = lane >> 4, ll = lane & 15;
                float inv = 1.f / s[r];
                float4 bv = *(const float4*)(bias + r * 64 + 4 * ll);
                ushort4 hv;
                hv.x = bf16_rne(fmaxf(fmaf(acc[r][0], inv, bv.x), 0.f));
                hv.y = bf16_rne(fmaxf(fmaf(acc[r][1], inv, bv.y), 0.f));
                hv.z = bf16_rne(fmaxf(fmaf(acc[r][2], inv, bv.z), 0.f));
                hv.w = bf16_rne(fmaxf(fmaf(acc[r][3], inv, bv.w), 0.f));
                *(ushort4*)&oh1[(size_t)node * HC + r * 64 + 4 * ll] = hv;
            }
        } else {
            if (lane < 16) {
                float i0v = 1.f / s[0], i1v = 1.f / s[1], i2v = 1.f / s[2];
                float4 bv = *(const float4*)(bias + 4 * l);
                float4 o;
                o.x = fmaxf((acc[0][0]*i0v + acc[1][0]*i1v + acc[2][0]*i2v) * (1.f/3.f) + bv.x, 0.f);
                o.y = fmaxf((acc[0][1]*i0v + acc[1][1]*i1v + acc[2][1]*i2v) * (1.f/3.f) + bv.y, 0.f);
                o.z = fmaxf((acc[0][2]*i0v + acc[1][2]*i1v + acc[2][2]*i2v) * (1.f/3.f) + bv.z, 0.f);
                o.w = fmaxf((acc[0][3]*i0v + acc[1][3]*i1v + acc[2][3]*i2v) * (1.f/3.f) + bv.w, 0.f);
                *(float4*)&out[(size_t)node * CC + 4 * l] = o;
            }
        }
    }
}

// ---------------------------------------------------------------------------
// Global mean pool: batch is SORTED -> running per-graph sums, flush on change.
// ---------------------------------------------------------------------------
#define POOL_BLOCKS 384
__global__ __launch_bounds__(256) void pool_kernel(
    const float* __restrict__ h2, const int* __restrict__ batch,
    float* __restrict__ pool, float* __restrict__ cnt, int n)
{
    const int c   = threadIdx.x & 63;
    const int sub = threadIdx.x >> 6;
    const int per = (n + gridDim.x - 1) / gridDim.x;
    const int n0  = blockIdx.x * per;
    const int n1  = min(n0 + per, n);

    float run = 0.f;
    float crun = 0.f;
    int curg = -1;
    for (int node = n0 + sub; node < n1; node += 4) {
        int g = batch[node];
        if (g != curg) {
            if (curg >= 0) {
                atomicAdd(&pool[curg * CC + c], run);
                if (c == 0) atomicAdd(&cnt[curg], crun);
            }
            run = 0.f; crun = 0.f; curg = g;
        }
        run += h2[(size_t)node * CC + c];
        crun += 1.f;
    }
    if (curg >= 0) {
        atomicAdd(&pool[curg * CC + c], run);
        if (c == 0) atomicAdd(&cnt[curg], crun);
    }
}

__global__ void head_kernel(const float* __restrict__ pool, const float* __restrict__ cnt,
                            const float* __restrict__ Wc, const float* __restrict__ bc,
                            float* __restrict__ outp) {
    __shared__ float lg[GG][NCLS];
    int t = threadIdx.x;
    if (t < GG * NCLS) {
        int g = t / NCLS, k = t % NCLS;
        float invc = 1.f / fmaxf(cnt[g], 1.f);
        float a = 0.f;
        for (int c = 0; c < CC; ++c) a += pool[g * CC + c] * Wc[c * NCLS + k];
        lg[g][k] = a * invc + bc[k];
    }
    __syncthreads();
    if (t < GG) {
        float mx = -1e30f;
        for (int k = 0; k < NCLS; ++k) mx = fmaxf(mx, lg[t][k]);
        float ssum = 0.f; float e[NCLS];
        for (int k = 0; k < NCLS; ++k) { e[k] = __expf(lg[t][k] - mx); ssum += e[k]; }
        for (int k = 0; k < NCLS; ++k) outp[t * NCLS + k] = e[k] / ssum;
    }
}

// ---------------------------------------------------------------------------
extern "C" void kernel_launch(void* const* d_in, const int* in_sizes, int n_in,
                              void* d_out, int out_size, void* d_ws, size_t ws_size,
                              hipStream_t stream) {
    const float* x     = (const float*)d_in[0];
    const int*   ei    = (const int*)d_in[1];
    const int*   batch = (const int*)d_in[2];
    const float* Wl1   = (const float*)d_in[3];
    const float* Wr1   = (const float*)d_in[4];
    const float* att1  = (const float*)d_in[5];
    const float* b1    = (const float*)d_in[6];
    const float* Wl2   = (const float*)d_in[7];
    const float* Wr2   = (const float*)d_in[8];
    const float* att2  = (const float*)d_in[9];
    const float* b2    = (const float*)d_in[10];
    const float* Wc    = (const float*)d_in[11];
    const float* bc    = (const float*)d_in[12];

    const int n = in_sizes[2];        // 50000 nodes
    const int E = in_sizes[1] / 2;    // 800000 edges
    const int* srcv = ei;
    const int* dstv = ei + E;

    // workspace layout
    char* base = (char*)d_ws;
    size_t off = 0;
    auto alloc = [&](size_t bytes) -> char* {
        char* p = base + off;
        off = (off + bytes + 255) & ~(size_t)255;
        return p;
    };
    int*   deg      = (int*)  alloc((size_t)n * 4);
    int*   cursor   = (int*)  alloc((size_t)n * 4);
    int*   rowp     = (int*)  alloc((size_t)(n + 1) * 4);
    int*   partials = (int*)  alloc(256 * 4);
    int*   colv     = (int*)  alloc((size_t)(E + n) * 4);
    u16*   xlp      = (u16*)  alloc((size_t)n * HC * 2);   // packed fp16 [grp][head][4]
    u16*   xrp      = (u16*)  alloc((size_t)n * HC * 2);
    u16*   h1b      = (u16*)  alloc((size_t)n * HC * 2);   // h1 bf16 row-major
    float* h2       = (float*)alloc((size_t)n * CC * 4);
    float* pool     = (float*)alloc((size_t)GG * (CC + 1) * 4);
    float* cnt      = pool + GG * CC;
    u16*   Bl1      = (u16*)  alloc((size_t)FF * HC * 2);
    u16*   Br1      = (u16*)  alloc((size_t)FF * HC * 2);
    u16*   Bl2      = (u16*)  alloc((size_t)HC * HC * 2);
    u16*   Br2      = (u16*)  alloc((size_t)HC * HC * 2);

    // --- CSR build with explicit self-loops ---
    hipMemsetAsync(deg, 0, (size_t)n * 4, stream);
    count_deg<<<(E + 255) / 256, 256, 0, stream>>>(dstv, deg, E);
    int nchunks = (n + 2047) / 2048;
    scan_local<<<nchunks, 256, 0, stream>>>(deg, rowp + 1, partials, n);
    scan_finish<<<(n + 255) / 256, 256, 0, stream>>>(rowp, cursor, partials, colv, n, nchunks);
    fill_csr<<<(E + 255) / 256, 256, 0, stream>>>(srcv, dstv, cursor, colv, E);

    // --- prep: weights -> frag-major bf16 (+pool zero) ---
    const int prep_total = 2 * FF * HC + 2 * HC * HC;
    prep_all<<<(prep_total + 255) / 256, 256, 0, stream>>>(
        Wl1, Wr1, Wl2, Wr2, Bl1, Br1, Bl2, Br2, pool);

    const int gblocks = (n + 31) / 32;

    // --- layer 1 (A = fp32 x, converted in-register) ---
    mfma_gemm<FF, true><<<gblocks, 256, 0, stream>>>(
        x, nullptr, Bl1, Br1, xlp, xrp, n);
    gat_agg<1><<<GAT_BLOCKS, 256, 0, stream>>>(xlp, xrp, rowp, colv, att1, b1,
                                               nullptr, h1b, n);

    // --- layer 2 (A = bf16 h1) ---
    mfma_gemm<HC, false><<<gblocks, 256, 0, stream>>>(
        nullptr, h1b, Bl2, Br2, xlp, xrp, n);
    gat_agg<0><<<GAT_BLOCKS, 256, 0, stream>>>(xlp, xrp, rowp, colv, att2, b2,
                                               h2, nullptr, n);

    // --- pool + head ---
    pool_kernel<<<POOL_BLOCKS, 256, 0, stream>>>(h2, batch, pool, cnt, n);
    head_kernel<<<1, 256, 0, stream>>>(pool, cnt, Wc, bc, (float*)d_out);
}

// Round 16
// 308.911 us; speedup vs baseline: 1.0806x; 1.0806x over previous
//
#include <hip/hip_runtime.h>
#include <hip/hip_bf16.h>
#include <stdint.h>

// Problem constants (from reference)
#define NN 50000
#define EE 800000
#define FF 128
#define HH 3
#define CC 64
#define GG 16
#define NCLS 10
#define HC (HH*CC)   // 192

#define LOG2E 1.4426950408889634f

typedef uint16_t u16;
typedef __attribute__((ext_vector_type(8))) short short8;
typedef __attribute__((ext_vector_type(4))) float f32x4;
typedef __attribute__((ext_vector_type(2))) _Float16 f16x2;

// ---------------------------------------------------------------------------
// bf16 RNE + fp16 bit helpers
// ---------------------------------------------------------------------------
__device__ __forceinline__ u16 bf16_rne(float x) {
    uint32_t u = __float_as_uint(x);
    u += 0x7fffu + ((u >> 16) & 1u);
    return (u16)(u >> 16);
}
__device__ __forceinline__ u16 f16_bits(float x) {
    _Float16 h = (_Float16)x;
    return __builtin_bit_cast(unsigned short, h);
}

// ---------------------------------------------------------------------------
// 16-lane (quarter-wave) sum via DPP row-scan + lane15 broadcast.
// ---------------------------------------------------------------------------
__device__ __forceinline__ float qsum16(float x) {
    #define DPP_ADD(ctrl) \
        x += __int_as_float(__builtin_amdgcn_update_dpp(0, __float_as_int(x), ctrl, 0xf, 0xf, true))
    DPP_ADD(0x111);  // row_shr:1
    DPP_ADD(0x112);  // row_shr:2
    DPP_ADD(0x114);  // row_shr:4
    DPP_ADD(0x118);  // row_shr:8
    #undef DPP_ADD
    return __int_as_float(__builtin_amdgcn_ds_swizzle(__float_as_int(x), 0x1F0));
}

// ---------------------------------------------------------------------------
// CSR build (WITH explicit self-loops)
// ---------------------------------------------------------------------------
__global__ void count_deg(const int* __restrict__ dst, int* __restrict__ deg, int E) {
    int i = blockIdx.x * blockDim.x + threadIdx.x;
    if (i < E) atomicAdd(&deg[dst[i]], 1);
}

__global__ __launch_bounds__(256) void scan_local(const int* __restrict__ deg,
                                                  int* __restrict__ rowp1,
                                                  int* __restrict__ partials, int n) {
    __shared__ int sums[256];
    int base = blockIdx.x * 2048 + threadIdx.x * 8;
    int v[8]; int run = 0;
    #pragma unroll
    for (int i = 0; i < 8; ++i) {
        int x = (base + i < n) ? deg[base + i] + 1 : 0;   // +1: self-loop slot
        run += x; v[i] = run;
    }
    sums[threadIdx.x] = run;
    __syncthreads();
    for (int off = 1; off < 256; off <<= 1) {
        int t = (threadIdx.x >= off) ? sums[threadIdx.x - off] : 0;
        __syncthreads();
        sums[threadIdx.x] += t;
        __syncthreads();
    }
    int prefix = (threadIdx.x > 0) ? sums[threadIdx.x - 1] : 0;
    #pragma unroll
    for (int i = 0; i < 8; ++i)
        if (base + i < n) rowp1[base + i] = v[i] + prefix;
    if (threadIdx.x == 255) partials[blockIdx.x] = sums[255];
}

// Fused: partials exclusive-prefix, rowp finalize, cursor init, self-loop write.
__global__ __launch_bounds__(256) void scan_finish(
    int* __restrict__ rowp, int* __restrict__ cursor, const int* __restrict__ partials,
    int* __restrict__ colv, int n, int nchunks) {
    __shared__ int pre[32];
    int t = threadIdx.x;
    if (t < 32) {
        int s = 0;
        for (int b = 0; b < nchunks && b < t; ++b) s += partials[b];
        pre[t] = s;
    }
    __syncthreads();
    int i = blockIdx.x * blockDim.x + t;
    if (i == 0) { rowp[0] = 0; cursor[0] = 0; }
    if (i < n) {
        int v = rowp[1 + i] + pre[i >> 11];
        rowp[1 + i] = v;
        colv[v - 1] = i;                 // self-loop in last slot of row i
        if (i < n - 1) cursor[i + 1] = v;
    }
}

__global__ void fill_csr(const int* __restrict__ src, const int* __restrict__ dst,
                         int* __restrict__ cursor, int* __restrict__ colv, int E) {
    int i = blockIdx.x * blockDim.x + threadIdx.x;
    if (i < E) {
        int pos = atomicAdd(&cursor[dst[i]], 1);
        colv[pos] = src[i];
    }
}

// ---------------------------------------------------------------------------
// Prep weights: [K][192] fp32 -> FRAG-MAJOR bf16 (MFMA B operand).
// Also zeroes the pool/cnt accumulators.
// ---------------------------------------------------------------------------
__global__ void prep_all(const float* __restrict__ Wl1, const float* __restrict__ Wr1,
                         const float* __restrict__ Wl2, const float* __restrict__ Wr2,
                         u16* l1, u16* r1, u16* l2, u16* r2,
                         float* __restrict__ pool) {
    int idx = blockIdx.x * blockDim.x + threadIdx.x;
    if (idx < GG * (CC + 1)) pool[idx] = 0.f;
    const int S1 = FF * HC, S2 = HC * HC;
    const float* B; u16* H; int K, f;
    if (idx < S1)                { B = Wl1; H = l1; K = FF; f = idx; }
    else if (idx < 2*S1)         { B = Wr1; H = r1; K = FF; f = idx - S1; }
    else if (idx < 2*S1 + S2)    { B = Wl2; H = l2; K = HC; f = idx - 2*S1; }
    else if (idx < 2*S1 + 2*S2)  { B = Wr2; H = r2; K = HC; f = idx - 2*S1 - S2; }
    else return;
    const int KB = K / 32;
    int j    = f & 7;
    int lane = (f >> 3) & 63;
    int rest = f >> 9;
    int kb    = rest % KB;
    int ntile = rest / KB;
    int n = ntile * 16 + (lane & 15);
    int k = kb * 32 + (lane >> 4) * 8 + j;
    H[f] = bf16_rne(B[k * HC + n]);
}

// ---------------------------------------------------------------------------
// Pure-bf16 MFMA dual GEMM: C1 = A@B1, C2 = A@B2, both emitted as packed FP16
// gather layout [node][16 lane-groups][3 head][4 chan] (384B/row):
//   u16 index of (chan c, head h) = (c>>2)*12 + h*4 + (c&3)
// 32-row M-tiles; A frags direct from global; CVTIN: fp32 A -> bf16 in-reg.
// K-loop touches no LDS -> epilogue needs only ONE barrier (two 16KB planes).
// ---------------------------------------------------------------------------
template<int K, bool CVTIN>
__global__ __launch_bounds__(256) void mfma_gemm(
    const float* __restrict__ Af, const u16* __restrict__ Ab,
    const u16* __restrict__ B1, const u16* __restrict__ B2,
    u16* __restrict__ C1p, u16* __restrict__ C2p, int M)
{
    constexpr int KB = K / 32;
    __shared__ __align__(16) u16 smem[2][32 * 256];

    const int tid  = threadIdx.x;
    const int w    = tid >> 6;
    const int lane = tid & 63;
    const int m0   = blockIdx.x * 32;
    const int frow = lane & 15;
    const int fkc  = lane >> 4;

    f32x4 acc[2][3][2];
    #pragma unroll
    for (int mt = 0; mt < 2; ++mt)
        #pragma unroll
        for (int nt = 0; nt < 3; ++nt)
            #pragma unroll
            for (int rt = 0; rt < 2; ++rt)
                acc[mt][nt][rt] = (f32x4){0.f, 0.f, 0.f, 0.f};

    int arow[2];
    arow[0] = min(m0 + frow, M - 1);
    arow[1] = min(m0 + 16 + frow, M - 1);

    const u16* bb[2][3];
    #pragma unroll
    for (int mt = 0; mt < 2; ++mt)
        #pragma unroll
        for (int nt = 0; nt < 3; ++nt)
            bb[mt][nt] = (mt ? B2 : B1) + ((size_t)(w * 3 + nt) * KB * 64 + lane) * 8;

    #pragma unroll
    for (int kb = 0; kb < KB; ++kb) {
        short8 af[2];
        #pragma unroll
        for (int rt = 0; rt < 2; ++rt) {
            if constexpr (CVTIN) {
                const float* ap = Af + (size_t)arow[rt] * K + kb * 32 + fkc * 8;
                float4 a0 = *(const float4*)ap;
                float4 a1 = *(const float4*)(ap + 4);
                af[rt] = (short8){(short)bf16_rne(a0.x), (short)bf16_rne(a0.y),
                                  (short)bf16_rne(a0.z), (short)bf16_rne(a0.w),
                                  (short)bf16_rne(a1.x), (short)bf16_rne(a1.y),
                                  (short)bf16_rne(a1.z), (short)bf16_rne(a1.w)};
            } else {
                af[rt] = *(const short8*)(Ab + (size_t)arow[rt] * K + kb * 32 + fkc * 8);
            }
        }
        #pragma unroll
        for (int mt = 0; mt < 2; ++mt)
            #pragma unroll
            for (int nt = 0; nt < 3; ++nt) {
                short8 b = *(const short8*)(bb[mt][nt] + kb * 512);
                #pragma unroll
                for (int rt = 0; rt < 2; ++rt)
                    acc[mt][nt][rt] = __builtin_amdgcn_mfma_f32_16x16x32_bf16(af[rt], b, acc[mt][nt][rt], 0, 0, 0);
            }
    }

    // ---- epilogue: repack through LDS (two planes, ONE barrier), coalesced stores
    const int q4 = (lane >> 4) * 4;
    #pragma unroll
    for (int mt = 0; mt < 2; ++mt) {
        #pragma unroll
        for (int nt = 0; nt < 3; ++nt) {
            int col = w * 48 + nt * 16 + frow;   // 0..191
            int c = col & 63, h = col >> 6;
            int u = (c >> 2) * 12 + h * 4 + (c & 3);   // fp16 pair-packed layout
            int chunk = u >> 3, within = u & 7;
            #pragma unroll
            for (int rt = 0; rt < 2; ++rt)
                #pragma unroll
                for (int r = 0; r < 4; ++r) {
                    int lrow = rt * 16 + q4 + r;
                    smem[mt][lrow * 256 + ((chunk ^ (lrow & 7)) << 3) + within] =
                        f16_bits(acc[mt][nt][rt][r]);
                }
        }
    }
    __syncthreads();
    #pragma unroll
    for (int mt = 0; mt < 2; ++mt) {
        u16* C = mt ? C2p : C1p;
        #pragma unroll
        for (int i = 0; i < 3; ++i) {
            int idx  = tid + 256 * i;       // 16B chunk id, 0..767
            int lrow = idx / 24;
            int coff = idx % 24;
            if (m0 + lrow < M)
                *(uint4*)(C + (size_t)(m0 + lrow) * HC + coff * 8) =
                    *(const uint4*)&smem[mt][lrow * 256 + ((coff ^ (lrow & 7)) << 3)];
        }
    }
}

// ---------------------------------------------------------------------------
// GATv2 aggregation (r12 best-measured form): one wave per node, FOUR edges
// per wave (one per 16-lane quarter), 4 channels per lane, 24B fp16 gather
// ([head][4chan] per lane). Packed-f16 add/leaky + v_dot2_f32_f16 dot;
// f32 p*v accumulation. Self-loops IN the CSR. DPP row-scan reduce;
// no-max softmax (exp2 domain).
// ---------------------------------------------------------------------------
template<bool MASK>
__device__ __forceinline__ void gat_quad(
    int i0, int q, int l, int beg, int cnt, int cm1,
    const int* __restrict__ colv, const u16* __restrict__ xlp,
    const f16x2 attv[3][2], const f16x2 xrv[3][2],
    float s[3], float acc[3][4])
{
    int idx = i0 + q;
    int iq  = MASK ? min(idx, cm1) : idx;
    int src = colv[beg + iq];
    const u16* p = xlp + (size_t)src * HC + l * 12;
    uint4 q0 = *(const uint4*)p;
    uint2 q1 = *(const uint2*)(p + 8);
    f16x2 vp[3][2];
    vp[0][0] = __builtin_bit_cast(f16x2, q0.x);
    vp[0][1] = __builtin_bit_cast(f16x2, q0.y);
    vp[1][0] = __builtin_bit_cast(f16x2, q0.z);
    vp[1][1] = __builtin_bit_cast(f16x2, q0.w);
    vp[2][0] = __builtin_bit_cast(f16x2, q1.x);
    vp[2][1] = __builtin_bit_cast(f16x2, q1.y);
    const f16x2 k02 = {(_Float16)0.2f, (_Float16)0.2f};
    #pragma unroll
    for (int r = 0; r < 3; ++r) {
        f16x2 t0 = vp[r][0] + xrv[r][0];
        f16x2 t1 = vp[r][1] + xrv[r][1];
        t0 = __builtin_elementwise_max(t0, t0 * k02);
        t1 = __builtin_elementwise_max(t1, t1 * k02);
        float d = __builtin_amdgcn_fdot2(t0, attv[r][0], 0.f, false);
        d = __builtin_amdgcn_fdot2(t1, attv[r][1], d, false);
        d = qsum16(d);
        float pe = __builtin_amdgcn_exp2f(d);
        if (MASK) pe = (idx < cnt) ? pe : 0.f;
        s[r] += pe;
        acc[r][0] = fmaf(pe, (float)vp[r][0][0], acc[r][0]);
        acc[r][1] = fmaf(pe, (float)vp[r][0][1], acc[r][1]);
        acc[r][2] = fmaf(pe, (float)vp[r][1][0], acc[r][2]);
        acc[r][3] = fmaf(pe, (float)vp[r][1][1], acc[r][3]);
    }
}

template<int CONCAT>
__global__ __launch_bounds__(256) void gat_agg(
    const u16* __restrict__ xlp, const u16* __restrict__ xrp,
    const int* __restrict__ rowp, const int* __restrict__ colv,
    const float* __restrict__ att, const float* __restrict__ bias,
    float* __restrict__ out, u16* __restrict__ oh1, int n)
{
    const int wave = threadIdx.x >> 6;
    const int lane = threadIdx.x & 63;
    const int node = __builtin_amdgcn_readfirstlane(blockIdx.x * 4 + wave);
    if (node >= n) return;
    const int q = lane >> 4;   // quarter = edge slot
    const int l = lane & 15;   // channel group (channels 4l..4l+3)

    f16x2 attv[3][2], xrv[3][2];
    #pragma unroll
    for (int r = 0; r < 3; ++r) {
        float4 a4 = *(const float4*)(att + r * 64 + 4 * l);
        attv[r][0] = (f16x2){(_Float16)(a4.x * LOG2E), (_Float16)(a4.y * LOG2E)};
        attv[r][1] = (f16x2){(_Float16)(a4.z * LOG2E), (_Float16)(a4.w * LOG2E)};
    }
    {
        const u16* p = xrp + (size_t)node * HC + l * 12;
        uint4 x0 = *(const uint4*)p;
        uint2 x1 = *(const uint2*)(p + 8);
        xrv[0][0] = __builtin_bit_cast(f16x2, x0.x);
        xrv[0][1] = __builtin_bit_cast(f16x2, x0.y);
        xrv[1][0] = __builtin_bit_cast(f16x2, x0.z);
        xrv[1][1] = __builtin_bit_cast(f16x2, x0.w);
        xrv[2][0] = __builtin_bit_cast(f16x2, x1.x);
        xrv[2][1] = __builtin_bit_cast(f16x2, x1.y);
    }

    float s[3] = {0.f, 0.f, 0.f};
    float acc[3][4] = {{0.f}};

    const int beg = rowp[node];
    const int cnt = rowp[node + 1] - beg;   // includes self-loop
    const int cm1 = cnt - 1;

    int i0 = 0;
    const int nfull = cnt & ~3;
    #pragma unroll 2
    for (; i0 < nfull; i0 += 4)
        gat_quad<false>(i0, q, l, beg, cnt, cm1, colv, xlp, attv, xrv, s, acc);
    if (i0 < cnt)
        gat_quad<true>(i0, q, l, beg, cnt, cm1, colv, xlp, attv, xrv, s, acc);

    // combine quarters (xor16) and halves (xor32)
    #pragma unroll
    for (int r = 0; r < 3; ++r) {
        s[r] += __shfl_xor(s[r], 16, 64);
        s[r] += __shfl_xor(s[r], 32, 64);
        #pragma unroll
        for (int j = 0; j < 4; ++j) {
            acc[r][j] += __shfl_xor(acc[r][j], 16, 64);
            acc[r][j] += __shfl_xor(acc[r][j], 32, 64);
        }
    }

    if (CONCAT) {
        if (lane < 48) {
            int r = lane >> 4, ll = lane & 15;
            float inv = 1.f / s[r];
            float4 bv = *(const float4*)(bias + r * 64 + 4 * ll);
            ushort4 hv;
            hv.x = bf16_rne(fmaxf(fmaf(acc[r][0], inv, bv.x), 0.f));
            hv.y = bf16_rne(fmaxf(fmaf(acc[r][1], inv, bv.y), 0.f));
            hv.z = bf16_rne(fmaxf(fmaf(acc[r][2], inv, bv.z), 0.f));
            hv.w = bf16_rne(fmaxf(fmaf(acc[r][3], inv, bv.w), 0.f));
            *(ushort4*)&oh1[(size_t)node * HC + r * 64 + 4 * ll] = hv;
        }
    } else {
        if (lane < 16) {
            float i0v = 1.f / s[0], i1v = 1.f / s[1], i2v = 1.f / s[2];
            float4 bv = *(const float4*)(bias + 4 * l);
            float4 o;
            o.x = fmaxf((acc[0][0]*i0v + acc[1][0]*i1v + acc[2][0]*i2v) * (1.f/3.f) + bv.x, 0.f);
            o.y = fmaxf((acc[0][1]*i0v + acc[1][1]*i1v + acc[2][1]*i2v) * (1.f/3.f) + bv.y, 0.f);
            o.z = fmaxf((acc[0][2]*i0v + acc[1][2]*i1v + acc[2][2]*i2v) * (1.f/3.f) + bv.z, 0.f);
            o.w = fmaxf((acc[0][3]*i0v + acc[1][3]*i1v + acc[2][3]*i2v) * (1.f/3.f) + bv.w, 0.f);
            *(float4*)&out[(size_t)node * CC + 4 * l] = o;
        }
    }
}

// ---------------------------------------------------------------------------
// Global mean pool: batch is SORTED -> running per-graph sums, flush on change.
// ---------------------------------------------------------------------------
#define POOL_BLOCKS 384
__global__ __launch_bounds__(256) void pool_kernel(
    const float* __restrict__ h2, const int* __restrict__ batch,
    float* __restrict__ pool, float* __restrict__ cnt, int n)
{
    const int c   = threadIdx.x & 63;
    const int sub = threadIdx.x >> 6;
    const int per = (n + gridDim.x - 1) / gridDim.x;
    const int n0  = blockIdx.x * per;
    const int n1  = min(n0 + per, n);

    float run = 0.f;
    float crun = 0.f;
    int curg = -1;
    for (int node = n0 + sub; node < n1; node += 4) {
        int g = batch[node];
        if (g != curg) {
            if (curg >= 0) {
                atomicAdd(&pool[curg * CC + c], run);
                if (c == 0) atomicAdd(&cnt[curg], crun);
            }
            run = 0.f; crun = 0.f; curg = g;
        }
        run += h2[(size_t)node * CC + c];
        crun += 1.f;
    }
    if (curg >= 0) {
        atomicAdd(&pool[curg * CC + c], run);
        if (c == 0) atomicAdd(&cnt[curg], crun);
    }
}

__global__ void head_kernel(const float* __restrict__ pool, const float* __restrict__ cnt,
                            const float* __restrict__ Wc, const float* __restrict__ bc,
                            float* __restrict__ outp) {
    __shared__ float lg[GG][NCLS];
    int t = threadIdx.x;
    if (t < GG * NCLS) {
        int g = t / NCLS, k = t % NCLS;
        float invc = 1.f / fmaxf(cnt[g], 1.f);
        float a = 0.f;
        for (int c = 0; c < CC; ++c) a += pool[g * CC + c] * Wc[c * NCLS + k];
        lg[g][k] = a * invc + bc[k];
    }
    __syncthreads();
    if (t < GG) {
        float mx = -1e30f;
        for (int k = 0; k < NCLS; ++k) mx = fmaxf(mx, lg[t][k]);
        float ssum = 0.f; float e[NCLS];
        for (int k = 0; k < NCLS; ++k) { e[k] = __expf(lg[t][k] - mx); ssum += e[k]; }
        for (int k = 0; k < NCLS; ++k) outp[t * NCLS + k] = e[k] / ssum;
    }
}

// ---------------------------------------------------------------------------
extern "C" void kernel_launch(void* const* d_in, const int* in_sizes, int n_in,
                              void* d_out, int out_size, void* d_ws, size_t ws_size,
                              hipStream_t stream) {
    const float* x     = (const float*)d_in[0];
    const int*   ei    = (const int*)d_in[1];
    const int*   batch = (const int*)d_in[2];
    const float* Wl1   = (const float*)d_in[3];
    const float* Wr1   = (const float*)d_in[4];
    const float* att1  = (const float*)d_in[5];
    const float* b1    = (const float*)d_in[6];
    const float* Wl2   = (const float*)d_in[7];
    const float* Wr2   = (const float*)d_in[8];
    const float* att2  = (const float*)d_in[9];
    const float* b2    = (const float*)d_in[10];
    const float* Wc    = (const float*)d_in[11];
    const float* bc    = (const float*)d_in[12];

    const int n = in_sizes[2];        // 50000 nodes
    const int E = in_sizes[1] / 2;    // 800000 edges
    const int* srcv = ei;
    const int* dstv = ei + E;

    // workspace layout
    char* base = (char*)d_ws;
    size_t off = 0;
    auto alloc = [&](size_t bytes) -> char* {
        char* p = base + off;
        off = (off + bytes + 255) & ~(size_t)255;
        return p;
    };
    int*   deg      = (int*)  alloc((size_t)n * 4);
    int*   cursor   = (int*)  alloc((size_t)n * 4);
    int*   rowp     = (int*)  alloc((size_t)(n + 1) * 4);
    int*   partials = (int*)  alloc(256 * 4);
    int*   colv     = (int*)  alloc((size_t)(E + n) * 4);
    u16*   xlp      = (u16*)  alloc((size_t)n * HC * 2);   // packed fp16 [grp][head][4]
    u16*   xrp      = (u16*)  alloc((size_t)n * HC * 2);
    u16*   h1b      = (u16*)  alloc((size_t)n * HC * 2);   // h1 bf16 row-major
    float* h2       = (float*)alloc((size_t)n * CC * 4);
    float* pool     = (float*)alloc((size_t)GG * (CC + 1) * 4);
    float* cnt      = pool + GG * CC;
    u16*   Bl1      = (u16*)  alloc((size_t)FF * HC * 2);
    u16*   Br1      = (u16*)  alloc((size_t)FF * HC * 2);
    u16*   Bl2      = (u16*)  alloc((size_t)HC * HC * 2);
    u16*   Br2      = (u16*)  alloc((size_t)HC * HC * 2);

    // --- CSR build with explicit self-loops ---
    hipMemsetAsync(deg, 0, (size_t)n * 4, stream);
    count_deg<<<(E + 255) / 256, 256, 0, stream>>>(dstv, deg, E);
    int nchunks = (n + 2047) / 2048;
    scan_local<<<nchunks, 256, 0, stream>>>(deg, rowp + 1, partials, n);
    scan_finish<<<(n + 255) / 256, 256, 0, stream>>>(rowp, cursor, partials, colv, n, nchunks);
    fill_csr<<<(E + 255) / 256, 256, 0, stream>>>(srcv, dstv, cursor, colv, E);

    // --- prep: weights -> frag-major bf16 (+pool zero) ---
    const int prep_total = 2 * FF * HC + 2 * HC * HC;
    prep_all<<<(prep_total + 255) / 256, 256, 0, stream>>>(
        Wl1, Wr1, Wl2, Wr2, Bl1, Br1, Bl2, Br2, pool);

    const int gblocks = (n + 31) / 32;

    // --- layer 1 (A = fp32 x, converted in-register) ---
    mfma_gemm<FF, true><<<gblocks, 256, 0, stream>>>(
        x, nullptr, Bl1, Br1, xlp, xrp, n);
    gat_agg<1><<<(n + 3) / 4, 256, 0, stream>>>(xlp, xrp, rowp, colv, att1, b1,
                                                nullptr, h1b, n);

    // --- layer 2 (A = bf16 h1) ---
    mfma_gemm<HC, false><<<gblocks, 256, 0, stream>>>(
        nullptr, h1b, Bl2, Br2, xlp, xrp, n);
    gat_agg<0><<<(n + 3) / 4, 256, 0, stream>>>(xlp, xrp, rowp, colv, att2, b2,
                                                h2, nullptr, n);

    // --- pool + head ---
    pool_kernel<<<POOL_BLOCKS, 256, 0, stream>>>(h2, batch, pool, cnt, n);
    head_kernel<<<1, 256, 0, stream>>>(pool, cnt, Wc, bc, (float*)d_out);
}